// Round 1
// baseline (566.757 us; speedup 1.0000x reference)
//
#include <hip/hip_runtime.h>
#include <math.h>

// Shapes: B=32, L=2048, E=512, H=512, V=32000
// Key insight: softmax over singleton axis == 1.0, so attn_weights == 1/2048
// exactly -> attention scores / emb / attn_W are dead code.
// c = relu(mean_L(encoder_out)); GRU cells; logits = c_out[31] @ out_W.T; log_softmax.
//
// d_out layout (fp32): logp [0,32000) | h_new [32000,64768) | attn_weights [64768,130304)

#define NC 16  // L-chunks for encoder reduction

// ---------------- K1: partial sums of encoder_out over L chunks ----------------
__global__ __launch_bounds__(256) void k_enc_partial(const float* __restrict__ enc,
                                                     float* __restrict__ partial) {
  const int tid = threadIdx.x;            // 0..255 (one float4 per thread = 1024 floats)
  const int ch  = blockIdx.x;             // 0..NC-1
  const int b   = blockIdx.y;             // 0..31
  const int rows = 2048 / NC;             // 128
  const float4* src = (const float4*)enc + ((size_t)b * 2048 + (size_t)ch * rows) * 256 + tid;
  float4 acc = make_float4(0.f, 0.f, 0.f, 0.f);
#pragma unroll 8
  for (int l = 0; l < rows; ++l) {
    float4 v = src[(size_t)l * 256];
    acc.x += v.x; acc.y += v.y; acc.z += v.z; acc.w += v.w;
  }
  ((float4*)partial)[((size_t)b * NC + ch) * 256 + tid] = acc;
}

// ---------------- K2: c = relu(mean) ----------------
__global__ __launch_bounds__(256) void k_c_final(const float* __restrict__ partial,
                                                 float* __restrict__ c) {
  const int idx = blockIdx.x * 256 + threadIdx.x;   // 0..32767
  const int b = idx >> 10, d = idx & 1023;
  float s = 0.f;
#pragma unroll
  for (int ch = 0; ch < NC; ++ch) s += partial[((size_t)b * NC + ch) * 1024 + d];
  s *= (1.0f / 2048.0f);
  c[idx] = s > 0.f ? s : 0.f;
}

// ---------------- K3: attn_weights = 1/2048 ----------------
__global__ __launch_bounds__(256) void k_attn_fill(float* __restrict__ out) {
  const int i = blockIdx.x * 256 + threadIdx.x;     // 0..65535
  out[64768 + i] = 1.0f / 2048.0f;
}

// ---------------- K4: bi-GRU cells, one wave per (dir, k) ----------------
__global__ __launch_bounds__(256) void k_gru(
    const float* __restrict__ c, const float* __restrict__ h,
    const float* __restrict__ Wih_f, const float* __restrict__ Whh_f,
    const float* __restrict__ bih_f, const float* __restrict__ bhh_f,
    const float* __restrict__ Wih_b, const float* __restrict__ Whh_b,
    const float* __restrict__ bih_b, const float* __restrict__ bhh_b,
    float* __restrict__ out) {
  const int lane = threadIdx.x & 63;
  const int wid  = (blockIdx.x * 256 + threadIdx.x) >> 6;  // 0..1023
  const int dir  = wid >> 9;
  const int k    = wid & 511;
  const float* Wih = dir ? Wih_b : Wih_f;
  const float* Whh = dir ? Whh_b : Whh_f;
  const float* bih = dir ? bih_b : bih_f;
  const float* bhh = dir ? bhh_b : bhh_f;
  const float4* Wih4 = (const float4*)Wih;
  const float4* Whh4 = (const float4*)Whh;

  float4 wr[4], wz[4], wn[4];
#pragma unroll
  for (int i = 0; i < 4; ++i) {
    wr[i] = Wih4[(size_t)k * 256 + i * 64 + lane];
    wz[i] = Wih4[(size_t)(k + 512) * 256 + i * 64 + lane];
    wn[i] = Wih4[(size_t)(k + 1024) * 256 + i * 64 + lane];
  }
  float4 ur[2], uz[2], un[2];
#pragma unroll
  for (int i = 0; i < 2; ++i) {
    ur[i] = Whh4[(size_t)k * 128 + i * 64 + lane];
    uz[i] = Whh4[(size_t)(k + 512) * 128 + i * 64 + lane];
    un[i] = Whh4[(size_t)(k + 1024) * 128 + i * 64 + lane];
  }
  const float4* c4 = (const float4*)c;
  const float4* h4 = (const float4*)h + (size_t)dir * 32 * 128;

  for (int b = 0; b < 32; ++b) {
    float pr = 0.f, pz = 0.f, pn = 0.f;
#pragma unroll
    for (int i = 0; i < 4; ++i) {
      float4 v = c4[b * 256 + i * 64 + lane];
      pr += v.x * wr[i].x + v.y * wr[i].y + v.z * wr[i].z + v.w * wr[i].w;
      pz += v.x * wz[i].x + v.y * wz[i].y + v.z * wz[i].z + v.w * wz[i].w;
      pn += v.x * wn[i].x + v.y * wn[i].y + v.z * wn[i].z + v.w * wn[i].w;
    }
    float qr = 0.f, qz = 0.f, qn = 0.f;
#pragma unroll
    for (int i = 0; i < 2; ++i) {
      float4 v = h4[b * 128 + i * 64 + lane];
      qr += v.x * ur[i].x + v.y * ur[i].y + v.z * ur[i].z + v.w * ur[i].w;
      qz += v.x * uz[i].x + v.y * uz[i].y + v.z * uz[i].z + v.w * uz[i].w;
      qn += v.x * un[i].x + v.y * un[i].y + v.z * un[i].z + v.w * un[i].w;
    }
#pragma unroll
    for (int off = 32; off; off >>= 1) {
      pr += __shfl_xor(pr, off, 64);
      pz += __shfl_xor(pz, off, 64);
      pn += __shfl_xor(pn, off, 64);
      qr += __shfl_xor(qr, off, 64);
      qz += __shfl_xor(qz, off, 64);
      qn += __shfl_xor(qn, off, 64);
    }
    if (lane == 0) {
      float ir = pr + bih[k];
      float iz = pz + bih[k + 512];
      float in_ = pn + bih[k + 1024];
      float hr = qr + bhh[k];
      float hz = qz + bhh[k + 512];
      float hn = qn + bhh[k + 1024];
      float r = 1.f / (1.f + expf(-(ir + hr)));
      float z = 1.f / (1.f + expf(-(iz + hz)));
      float n = tanhf(in_ + r * hn);
      float hp = h[(size_t)dir * 32 * 512 + (size_t)b * 512 + k];
      out[32000 + dir * 16384 + b * 512 + k] = (1.f - z) * n + z * hp;
    }
  }
}

// ---------------- K5: logits[v] = dot(c_out[31], out_W[v]) + out_b[v] ----------------
__global__ __launch_bounds__(256) void k_logits(const float* __restrict__ outW,
                                                const float* __restrict__ outb,
                                                const float* __restrict__ dout,
                                                float* __restrict__ logits) {
  const int lane = threadIdx.x & 63;
  const int v = (blockIdx.x * 256 + threadIdx.x) >> 6;  // 0..31999
  // c_out[31] = concat(h_f[31], h_b[31]) read from d_out's h_new region
  const float4* hf = (const float4*)(dout + 32000 + 31 * 512);
  const float4* hb = (const float4*)(dout + 32000 + 16384 + 31 * 512);
  const float4* W4 = (const float4*)outW + (size_t)v * 256;
  float p = 0.f;
#pragma unroll
  for (int i = 0; i < 4; ++i) {
    const int pos = i * 64 + lane;
    float4 cv = (pos < 128) ? hf[pos] : hb[pos - 128];
    float4 wv = W4[pos];
    p += cv.x * wv.x + cv.y * wv.y + cv.z * wv.z + cv.w * wv.w;
  }
#pragma unroll
  for (int off = 32; off; off >>= 1) p += __shfl_xor(p, off, 64);
  if (lane == 0) logits[v] = p + outb[v];
}

// ---------------- K6: single-block logsumexp over 32000 logits ----------------
__global__ __launch_bounds__(1024) void k_lse(const float* __restrict__ logits,
                                              float* __restrict__ scal) {
  __shared__ float red[16];
  __shared__ float gmax_s;
  const int tid = threadIdx.x, lane = tid & 63, w = tid >> 6;
  float m = -1e30f;
  for (int i = tid; i < 32000; i += 1024) m = fmaxf(m, logits[i]);
#pragma unroll
  for (int off = 32; off; off >>= 1) m = fmaxf(m, __shfl_xor(m, off, 64));
  if (lane == 0) red[w] = m;
  __syncthreads();
  if (tid == 0) {
    float mm = red[0];
    for (int i = 1; i < 16; ++i) mm = fmaxf(mm, red[i]);
    gmax_s = mm;
  }
  __syncthreads();
  const float gm = gmax_s;
  float s = 0.f;
  for (int i = tid; i < 32000; i += 1024) s += expf(logits[i] - gm);
#pragma unroll
  for (int off = 32; off; off >>= 1) s += __shfl_xor(s, off, 64);
  if (lane == 0) red[w] = s;
  __syncthreads();
  if (tid == 0) {
    float ss = 0.f;
    for (int i = 0; i < 16; ++i) ss += red[i];
    scal[0] = gm;
    scal[1] = logf(ss);
  }
}

// ---------------- K7: logp = logits - max - log(sumexp) ----------------
__global__ __launch_bounds__(256) void k_logp(const float* __restrict__ logits,
                                              const float* __restrict__ scal,
                                              float* __restrict__ out) {
  const int i = blockIdx.x * 256 + threadIdx.x;  // 0..31999
  out[i] = logits[i] - scal[0] - scal[1];
}

extern "C" void kernel_launch(void* const* d_in, const int* in_sizes, int n_in,
                              void* d_out, int out_size, void* d_ws, size_t ws_size,
                              hipStream_t stream) {
  // Input order per setup_inputs():
  // 0:x 1:h 2:encoder_out 3:emb 4:attn_W 5:attn_b 6:W_ih_f 7:W_hh_f 8:b_ih_f 9:b_hh_f
  // 10:W_ih_b 11:W_hh_b 12:b_ih_b 13:b_hh_b 14:out_W 15:out_b
  const float* h     = (const float*)d_in[1];
  const float* enc   = (const float*)d_in[2];
  const float* Wih_f = (const float*)d_in[6];
  const float* Whh_f = (const float*)d_in[7];
  const float* bih_f = (const float*)d_in[8];
  const float* bhh_f = (const float*)d_in[9];
  const float* Wih_b = (const float*)d_in[10];
  const float* Whh_b = (const float*)d_in[11];
  const float* bih_b = (const float*)d_in[12];
  const float* bhh_b = (const float*)d_in[13];
  const float* outW  = (const float*)d_in[14];
  const float* outb  = (const float*)d_in[15];
  float* out = (float*)d_out;
  float* ws  = (float*)d_ws;

  float* partial = ws;                    // 32*NC*1024 = 524288 floats
  float* cbuf    = partial + 32 * NC * 1024;  // 32768 floats
  float* logits  = cbuf + 32768;          // 32000 floats
  float* scal    = logits + 32000;        // 2 floats

  dim3 g1(NC, 32);
  k_enc_partial<<<g1, 256, 0, stream>>>(enc, partial);
  k_c_final<<<128, 256, 0, stream>>>(partial, cbuf);
  k_attn_fill<<<256, 256, 0, stream>>>(out);
  k_gru<<<256, 256, 0, stream>>>(cbuf, h, Wih_f, Whh_f, bih_f, bhh_f,
                                 Wih_b, Whh_b, bih_b, bhh_b, out);
  k_logits<<<8000, 256, 0, stream>>>(outW, outb, out, logits);
  k_lse<<<1, 1024, 0, stream>>>(logits, scal);
  k_logp<<<125, 256, 0, stream>>>(logits, scal, out);
}

// Round 2
// 541.297 us; speedup vs baseline: 1.0470x; 1.0470x over previous
//
#include <hip/hip_runtime.h>
#include <math.h>

// Shapes: B=32, L=2048, E=512, H=512, V=32000
// Dead code: softmax over singleton axis == 1.0 -> attn_weights == 1/2048 exactly
// -> x/emb/attn_W/attn_b never read; c = relu(mean_L(encoder_out)).
// Mandatory HBM: encoder_out 268 MB + out_W 131 MB + GRU weights 19 MB ~ 420 MB -> ~65 us floor.
//
// d_out layout (fp32): logp [0,32000) | h_new [32000,64768) | attn_weights [64768,130304)

#define NC 32  // L-chunks for encoder reduction (1024 blocks -> 4 blocks/CU)

// ---------------- K1: partial sums of encoder_out over L chunks ----------------
__global__ __launch_bounds__(256) void k_enc_partial(const float* __restrict__ enc,
                                                     float* __restrict__ partial) {
  const int tid = threadIdx.x;            // 0..255; one float4 each -> full 1024-float row
  const int ch  = blockIdx.x;             // 0..NC-1
  const int b   = blockIdx.y;             // 0..31
  const int rows = 2048 / NC;             // 64
  const float4* src = (const float4*)enc + ((size_t)b * 2048 + (size_t)ch * rows) * 256 + tid;
  float4 acc = make_float4(0.f, 0.f, 0.f, 0.f);
#pragma unroll 8
  for (int l = 0; l < rows; ++l) {
    float4 v = src[(size_t)l * 256];
    acc.x += v.x; acc.y += v.y; acc.z += v.z; acc.w += v.w;
  }
  ((float4*)partial)[((size_t)b * NC + ch) * 256 + tid] = acc;
}

// ---------------- K2: c = relu(mean)  (blocks 0..127)  +  attn_weights fill (blocks 128..383) ----------------
__global__ __launch_bounds__(256) void k_c_fill(const float* __restrict__ partial,
                                                float* __restrict__ c,
                                                float* __restrict__ out) {
  const int bid = blockIdx.x;
  if (bid < 128) {
    const int idx = bid * 256 + threadIdx.x;   // 0..32767
    const int b = idx >> 10, d = idx & 1023;
    float s = 0.f;
#pragma unroll
    for (int ch = 0; ch < NC; ++ch) s += partial[((size_t)b * NC + ch) * 1024 + d];
    s *= (1.0f / 2048.0f);
    c[idx] = s > 0.f ? s : 0.f;
  } else {
    const int i = (bid - 128) * 256 + threadIdx.x;  // 0..65535
    out[64768 + i] = 1.0f / 2048.0f;
  }
}

// ---------------- K3: bi-GRU cells, one wave per (dir, k) ----------------
__global__ __launch_bounds__(256) void k_gru(
    const float* __restrict__ c, const float* __restrict__ h,
    const float* __restrict__ Wih_f, const float* __restrict__ Whh_f,
    const float* __restrict__ bih_f, const float* __restrict__ bhh_f,
    const float* __restrict__ Wih_b, const float* __restrict__ Whh_b,
    const float* __restrict__ bih_b, const float* __restrict__ bhh_b,
    float* __restrict__ out) {
  const int lane = threadIdx.x & 63;
  const int wid  = (blockIdx.x * 256 + threadIdx.x) >> 6;  // 0..1023
  const int dir  = wid >> 9;
  const int k    = wid & 511;
  const float* Wih = dir ? Wih_b : Wih_f;
  const float* Whh = dir ? Whh_b : Whh_f;
  const float* bih = dir ? bih_b : bih_f;
  const float* bhh = dir ? bhh_b : bhh_f;
  const float4* Wih4 = (const float4*)Wih;
  const float4* Whh4 = (const float4*)Whh;

  float4 wr[4], wz[4], wn[4];
#pragma unroll
  for (int i = 0; i < 4; ++i) {
    wr[i] = Wih4[(size_t)k * 256 + i * 64 + lane];
    wz[i] = Wih4[(size_t)(k + 512) * 256 + i * 64 + lane];
    wn[i] = Wih4[(size_t)(k + 1024) * 256 + i * 64 + lane];
  }
  float4 ur[2], uz[2], un[2];
#pragma unroll
  for (int i = 0; i < 2; ++i) {
    ur[i] = Whh4[(size_t)k * 128 + i * 64 + lane];
    uz[i] = Whh4[(size_t)(k + 512) * 128 + i * 64 + lane];
    un[i] = Whh4[(size_t)(k + 1024) * 128 + i * 64 + lane];
  }
  // hoist biases out of the batch loop
  const float bkr = bih[k], bkz = bih[k + 512], bkn = bih[k + 1024];
  const float ckr = bhh[k], ckz = bhh[k + 512], ckn = bhh[k + 1024];

  const float4* c4 = (const float4*)c;
  const float4* h4 = (const float4*)h + (size_t)dir * 32 * 128;

  for (int b = 0; b < 32; ++b) {
    float pr = 0.f, pz = 0.f, pn = 0.f;
#pragma unroll
    for (int i = 0; i < 4; ++i) {
      float4 v = c4[b * 256 + i * 64 + lane];
      pr += v.x * wr[i].x + v.y * wr[i].y + v.z * wr[i].z + v.w * wr[i].w;
      pz += v.x * wz[i].x + v.y * wz[i].y + v.z * wz[i].z + v.w * wz[i].w;
      pn += v.x * wn[i].x + v.y * wn[i].y + v.z * wn[i].z + v.w * wn[i].w;
    }
    float qr = 0.f, qz = 0.f, qn = 0.f;
#pragma unroll
    for (int i = 0; i < 2; ++i) {
      float4 v = h4[b * 128 + i * 64 + lane];
      qr += v.x * ur[i].x + v.y * ur[i].y + v.z * ur[i].z + v.w * ur[i].w;
      qz += v.x * uz[i].x + v.y * uz[i].y + v.z * uz[i].z + v.w * uz[i].w;
      qn += v.x * un[i].x + v.y * un[i].y + v.z * un[i].z + v.w * un[i].w;
    }
#pragma unroll
    for (int off = 32; off; off >>= 1) {
      pr += __shfl_xor(pr, off, 64);
      pz += __shfl_xor(pz, off, 64);
      pn += __shfl_xor(pn, off, 64);
      qr += __shfl_xor(qr, off, 64);
      qz += __shfl_xor(qz, off, 64);
      qn += __shfl_xor(qn, off, 64);
    }
    if (lane == 0) {
      float r = 1.f / (1.f + expf(-(pr + bkr + qr + ckr)));
      float z = 1.f / (1.f + expf(-(pz + bkz + qz + ckz)));
      float n = tanhf(pn + bkn + r * (qn + ckn));
      float hp = h[(size_t)dir * 32 * 512 + (size_t)b * 512 + k];
      out[32000 + dir * 16384 + b * 512 + k] = (1.f - z) * n + z * hp;
    }
  }
}

// ---------------- K4: logits[v] = dot(c_out[31], out_W[v]) + out_b[v] ----------------
__global__ __launch_bounds__(256) void k_logits(const float* __restrict__ outW,
                                                const float* __restrict__ outb,
                                                const float* __restrict__ dout,
                                                float* __restrict__ logits) {
  const int lane = threadIdx.x & 63;
  const int v = (blockIdx.x * 256 + threadIdx.x) >> 6;  // 0..31999
  // c_out[31] = concat(h_f[31], h_b[31]) read from d_out's h_new region (L2-hot)
  const float4* hf = (const float4*)(dout + 32000 + 31 * 512);
  const float4* hb = (const float4*)(dout + 32000 + 16384 + 31 * 512);
  const float4* W4 = (const float4*)outW + (size_t)v * 256;
  float p = 0.f;
#pragma unroll
  for (int i = 0; i < 4; ++i) {
    const int pos = i * 64 + lane;
    float4 cv = (pos < 128) ? hf[pos] : hb[pos - 128];
    float4 wv = W4[pos];
    p += cv.x * wv.x + cv.y * wv.y + cv.z * wv.z + cv.w * wv.w;
  }
#pragma unroll
  for (int off = 32; off; off >>= 1) p += __shfl_xor(p, off, 64);
  if (lane == 0) logits[v] = p + outb[v];
}

// ---------------- K5: fused logsumexp + logp write (single block; logits are L2-hot) ----------------
__global__ __launch_bounds__(1024) void k_lse_logp(const float* __restrict__ logits,
                                                   float* __restrict__ out) {
  __shared__ float red[16];
  __shared__ float s_m, s_ls;
  const int tid = threadIdx.x, lane = tid & 63, w = tid >> 6;
  float m = -1e30f;
  for (int i = tid; i < 32000; i += 1024) m = fmaxf(m, logits[i]);
#pragma unroll
  for (int off = 32; off; off >>= 1) m = fmaxf(m, __shfl_xor(m, off, 64));
  if (lane == 0) red[w] = m;
  __syncthreads();
  if (tid == 0) {
    float mm = red[0];
    for (int i = 1; i < 16; ++i) mm = fmaxf(mm, red[i]);
    s_m = mm;
  }
  __syncthreads();
  const float gm = s_m;
  float s = 0.f;
  for (int i = tid; i < 32000; i += 1024) s += expf(logits[i] - gm);
#pragma unroll
  for (int off = 32; off; off >>= 1) s += __shfl_xor(s, off, 64);
  if (lane == 0) red[w] = s;
  __syncthreads();
  if (tid == 0) {
    float ss = 0.f;
    for (int i = 0; i < 16; ++i) ss += red[i];
    s_ls = logf(ss);
  }
  __syncthreads();
  const float sub = gm + s_ls;
  for (int i = tid; i < 32000; i += 1024) out[i] = logits[i] - sub;
}

extern "C" void kernel_launch(void* const* d_in, const int* in_sizes, int n_in,
                              void* d_out, int out_size, void* d_ws, size_t ws_size,
                              hipStream_t stream) {
  // 0:x 1:h 2:encoder_out 3:emb 4:attn_W 5:attn_b 6:W_ih_f 7:W_hh_f 8:b_ih_f 9:b_hh_f
  // 10:W_ih_b 11:W_hh_b 12:b_ih_b 13:b_hh_b 14:out_W 15:out_b
  const float* h     = (const float*)d_in[1];
  const float* enc   = (const float*)d_in[2];
  const float* Wih_f = (const float*)d_in[6];
  const float* Whh_f = (const float*)d_in[7];
  const float* bih_f = (const float*)d_in[8];
  const float* bhh_f = (const float*)d_in[9];
  const float* Wih_b = (const float*)d_in[10];
  const float* Whh_b = (const float*)d_in[11];
  const float* bih_b = (const float*)d_in[12];
  const float* bhh_b = (const float*)d_in[13];
  const float* outW  = (const float*)d_in[14];
  const float* outb  = (const float*)d_in[15];
  float* out = (float*)d_out;
  float* ws  = (float*)d_ws;

  float* partial = ws;                         // 32*NC*1024 floats (4 MB)
  float* cbuf    = partial + 32 * NC * 1024;   // 32768 floats
  float* logits  = cbuf + 32768;               // 32000 floats

  dim3 g1(NC, 32);
  k_enc_partial<<<g1, 256, 0, stream>>>(enc, partial);
  k_c_fill<<<384, 256, 0, stream>>>(partial, cbuf, out);
  k_gru<<<256, 256, 0, stream>>>(cbuf, h, Wih_f, Whh_f, bih_f, bhh_f,
                                 Wih_b, Whh_b, bih_b, bhh_b, out);
  k_logits<<<8000, 256, 0, stream>>>(outW, outb, out, logits);
  k_lse_logp<<<1, 1024, 0, stream>>>(logits, out);
}